// Round 2
// baseline (830.974 us; speedup 1.0000x reference)
//
#include <hip/hip_runtime.h>
#include <hip/hip_bf16.h>

// Problem constants (fixed by the reference)
#define HD   4096      // hidden
#define ID   14336     // intermediate
#define NB   64        // batch
#define NLUTN 4096
#define DSPLIT 8       // down-proj cross-block K split

typedef __attribute__((ext_vector_type(8))) short short8;   // 8 x bf16 bits = 4 VGPRs
typedef __attribute__((ext_vector_type(4))) float f32x4;    // MFMA accumulator

__device__ __forceinline__ unsigned short f2bf(float f) {
  __hip_bfloat16 h = __float2bfloat16(f);
  return __builtin_bit_cast(unsigned short, h);
}

// ---------------------------------------------------------------------------
// prep: x'_g[b][h] = bf16(x[b][h]*gsr[h]), x'_u likewise. 64*4096 elements.
// ---------------------------------------------------------------------------
__global__ __launch_bounds__(256) void prep_kernel(
    const float* __restrict__ x, const float* __restrict__ gsr,
    const float* __restrict__ usr,
    unsigned short* __restrict__ xg, unsigned short* __restrict__ xu)
{
  int t = blockIdx.x * 256 + threadIdx.x;          // 0..65535 float4s
  float4 xv = ((const float4*)x)[t];
  int hs = t & (HD/4 - 1);                         // float4 index within row
  float4 g = ((const float4*)gsr)[hs];
  float4 u = ((const float4*)usr)[hs];
  ushort4 og = make_ushort4(f2bf(xv.x*g.x), f2bf(xv.y*g.y), f2bf(xv.z*g.z), f2bf(xv.w*g.w));
  ushort4 ou = make_ushort4(f2bf(xv.x*u.x), f2bf(xv.y*u.y), f2bf(xv.z*u.z), f2bf(xv.w*u.w));
  ((ushort4*)xg)[t] = og;
  ((ushort4*)xu)[t] = ou;
}

// ---------------------------------------------------------------------------
// gate+up: 256-thread blocks (4 waves). Each wave handles one K-chunk of 1024
// for BOTH gate and up on a 16-row I-strip. LDS tree reduction, wave 0 does
// the silu*up*dsr epilogue. 896 blocks -> 3584 waves -> 4 blocks/CU (40KB LDS).
// 1-deep software prefetch of walk int4 loads hides global latency.
// ---------------------------------------------------------------------------
__global__ __launch_bounds__(256) void gate_up_kernel(
    const int* __restrict__ gw, const int* __restrict__ uw,
    const float* __restrict__ lutg_f, const float* __restrict__ lutu_f,
    const unsigned short* __restrict__ xg, const unsigned short* __restrict__ xu,
    const float* __restrict__ gsl, const float* __restrict__ usl,
    const float* __restrict__ dsr,
    unsigned short* __restrict__ hidden)
{
  __shared__ unsigned short lutg[NLUTN];   // 8 KB
  __shared__ unsigned short lutu[NLUTN];   // 8 KB
  __shared__ f32x4 red[3][64][8];          // 24 KB: waves 1..3 partials

  const int tid = threadIdx.x;

  // Stage LUTs as bf16 bits with all 256 threads
  #pragma unroll
  for (int i = tid; i < NLUTN/4; i += 256) {
    float4 g = ((const float4*)lutg_f)[i];
    float4 u = ((const float4*)lutu_f)[i];
    ((ushort4*)lutg)[i] = make_ushort4(f2bf(g.x), f2bf(g.y), f2bf(g.z), f2bf(g.w));
    ((ushort4*)lutu)[i] = make_ushort4(f2bf(u.x), f2bf(u.y), f2bf(u.z), f2bf(u.w));
  }
  __syncthreads();

  const int lane = tid & 63;
  const int wave = tid >> 6;          // 0..3 -> K-chunk
  const int col  = lane & 15;         // A row-in-strip / D batch col
  const int quad = lane >> 4;
  const int m0   = blockIdx.x * 16;
  const int kbeg = wave * (HD/4);     // 1024-wide chunk
  const int kend = kbeg + HD/4;

  const int* gp = gw + (size_t)(m0 + col) * HD + quad * 8;
  const int* up = uw + (size_t)(m0 + col) * HD + quad * 8;
  const unsigned short* xgp[4];
  const unsigned short* xup[4];
  #pragma unroll
  for (int t = 0; t < 4; ++t) {
    xgp[t] = xg + (size_t)(t*16 + col) * HD + quad * 8;
    xup[t] = xu + (size_t)(t*16 + col) * HD + quad * 8;
  }

  const f32x4 z = {0.f, 0.f, 0.f, 0.f};
  f32x4 accg[4] = {z, z, z, z};
  f32x4 accu[4] = {z, z, z, z};

  // prefetched walk indices
  int4 ga = *(const int4*)(gp + kbeg);
  int4 gb = *(const int4*)(gp + kbeg + 4);
  int4 ua = *(const int4*)(up + kbeg);
  int4 ub = *(const int4*)(up + kbeg + 4);

  for (int k0 = kbeg; k0 < kend; k0 += 32) {
    int4 cga = ga, cgb = gb, cua = ua, cub = ub;
    int kn = (k0 + 32 < kend) ? (k0 + 32) : kbeg;   // wave-uniform
    ga = *(const int4*)(gp + kn);
    gb = *(const int4*)(gp + kn + 4);
    ua = *(const int4*)(up + kn);
    ub = *(const int4*)(up + kn + 4);

    short8 afg, afu;
    afg[0] = (short)lutg[cga.x]; afg[1] = (short)lutg[cga.y];
    afg[2] = (short)lutg[cga.z]; afg[3] = (short)lutg[cga.w];
    afg[4] = (short)lutg[cgb.x]; afg[5] = (short)lutg[cgb.y];
    afg[6] = (short)lutg[cgb.z]; afg[7] = (short)lutg[cgb.w];
    afu[0] = (short)lutu[cua.x]; afu[1] = (short)lutu[cua.y];
    afu[2] = (short)lutu[cua.z]; afu[3] = (short)lutu[cua.w];
    afu[4] = (short)lutu[cub.x]; afu[5] = (short)lutu[cub.y];
    afu[6] = (short)lutu[cub.z]; afu[7] = (short)lutu[cub.w];

    #pragma unroll
    for (int t = 0; t < 4; ++t) {
      short8 bg = __builtin_bit_cast(short8, *(const int4*)(xgp[t] + k0));
      short8 bu = __builtin_bit_cast(short8, *(const int4*)(xup[t] + k0));
      accg[t] = __builtin_amdgcn_mfma_f32_16x16x32_bf16(afg, bg, accg[t], 0, 0, 0);
      accu[t] = __builtin_amdgcn_mfma_f32_16x16x32_bf16(afu, bu, accu[t], 0, 0, 0);
    }
  }

  // Inter-wave reduction: waves 1..3 publish, wave 0 reduces + epilogue.
  if (wave != 0) {
    #pragma unroll
    for (int t = 0; t < 4; ++t) {
      red[wave-1][lane][t]     = accg[t];
      red[wave-1][lane][4 + t] = accu[t];
    }
  }
  __syncthreads();
  if (wave == 0) {
    #pragma unroll
    for (int w = 0; w < 3; ++w)
      #pragma unroll
      for (int t = 0; t < 4; ++t) {
        f32x4 pg = red[w][lane][t];
        f32x4 pu = red[w][lane][4 + t];
        #pragma unroll
        for (int r = 0; r < 4; ++r) { accg[t][r] += pg[r]; accu[t][r] += pu[r]; }
      }

    // D mapping: col = lane&15 (batch), row = quad*4 + reg (i).
    const int mrow = m0 + quad * 4;
    float sg[4], su[4], sd[4];
    #pragma unroll
    for (int r = 0; r < 4; ++r) {
      sg[r] = 0.02f * gsl[mrow + r];
      su[r] = 0.02f * usl[mrow + r];
      sd[r] = dsr[mrow + r];
    }
    #pragma unroll
    for (int t = 0; t < 4; ++t) {
      int b = t*16 + col;
      ushort4 hv;
      float g0 = accg[t][0] * sg[0], u0 = accu[t][0] * su[0];
      float g1 = accg[t][1] * sg[1], u1 = accu[t][1] * su[1];
      float g2 = accg[t][2] * sg[2], u2 = accu[t][2] * su[2];
      float g3 = accg[t][3] * sg[3], u3 = accu[t][3] * su[3];
      hv.x = f2bf((g0 / (1.f + __expf(-g0))) * u0 * sd[0]);
      hv.y = f2bf((g1 / (1.f + __expf(-g1))) * u1 * sd[1]);
      hv.z = f2bf((g2 / (1.f + __expf(-g2))) * u2 * sd[2]);
      hv.w = f2bf((g3 / (1.f + __expf(-g3))) * u3 * sd[3]);
      *((ushort4*)(hidden + (size_t)b * ID + mrow)) = hv;
    }
  }
}

// ---------------------------------------------------------------------------
// down: out[b][h] = 0.02*dsl[h] * sum_i hidden[b][i]*lut_d[dw[h,i]]
// grid (HD/16, DSPLIT) 256-thread blocks; per-wave K = ID/(DSPLIT*4) = 448.
// 8192 waves -> 32 waves/CU (20 KB LDS -> 8 blocks/CU). In-block reduction,
// wave 0 does f32 atomicAdd epilogue.
// ---------------------------------------------------------------------------
__global__ __launch_bounds__(256) void down_kernel(
    const int* __restrict__ dw, const float* __restrict__ lutd_f,
    const unsigned short* __restrict__ hidden,
    const float* __restrict__ dsl,
    float* __restrict__ out)
{
  __shared__ unsigned short lutd[NLUTN];   // 8 KB
  __shared__ f32x4 red[3][64][4];          // 12 KB

  const int tid = threadIdx.x;
  #pragma unroll
  for (int i = tid; i < NLUTN/4; i += 256) {
    float4 d = ((const float4*)lutd_f)[i];
    ((ushort4*)lutd)[i] = make_ushort4(f2bf(d.x), f2bf(d.y), f2bf(d.z), f2bf(d.w));
  }
  __syncthreads();

  const int lane = tid & 63;
  const int wave = tid >> 6;
  const int col  = lane & 15;
  const int quad = lane >> 4;
  const int m0   = blockIdx.x * 16;                       // h strip
  const int kbeg = blockIdx.y * (ID / DSPLIT) + wave * (ID / (DSPLIT*4));
  const int kend = kbeg + (ID / (DSPLIT*4));              // 448 wide

  const int* dp = dw + (size_t)(m0 + col) * ID + quad * 8;
  const unsigned short* hp[4];
  #pragma unroll
  for (int t = 0; t < 4; ++t)
    hp[t] = hidden + (size_t)(t*16 + col) * ID + quad * 8;

  const f32x4 z = {0.f, 0.f, 0.f, 0.f};
  f32x4 acc[4] = {z, z, z, z};

  int4 da = *(const int4*)(dp + kbeg);
  int4 db = *(const int4*)(dp + kbeg + 4);

  for (int k0 = kbeg; k0 < kend; k0 += 32) {
    int4 cda = da, cdb = db;
    int kn = (k0 + 32 < kend) ? (k0 + 32) : kbeg;
    da = *(const int4*)(dp + kn);
    db = *(const int4*)(dp + kn + 4);

    short8 af;
    af[0] = (short)lutd[cda.x]; af[1] = (short)lutd[cda.y];
    af[2] = (short)lutd[cda.z]; af[3] = (short)lutd[cda.w];
    af[4] = (short)lutd[cdb.x]; af[5] = (short)lutd[cdb.y];
    af[6] = (short)lutd[cdb.z]; af[7] = (short)lutd[cdb.w];
    #pragma unroll
    for (int t = 0; t < 4; ++t) {
      short8 bh = __builtin_bit_cast(short8, *(const int4*)(hp[t] + k0));
      acc[t] = __builtin_amdgcn_mfma_f32_16x16x32_bf16(af, bh, acc[t], 0, 0, 0);
    }
  }

  if (wave != 0) {
    #pragma unroll
    for (int t = 0; t < 4; ++t) red[wave-1][lane][t] = acc[t];
  }
  __syncthreads();
  if (wave == 0) {
    #pragma unroll
    for (int w = 0; w < 3; ++w)
      #pragma unroll
      for (int t = 0; t < 4; ++t) {
        f32x4 p = red[w][lane][t];
        #pragma unroll
        for (int r = 0; r < 4; ++r) acc[t][r] += p[r];
      }

    const int mrow = m0 + quad * 4;
    float sc[4];
    #pragma unroll
    for (int r = 0; r < 4; ++r) sc[r] = 0.02f * dsl[mrow + r];
    #pragma unroll
    for (int t = 0; t < 4; ++t) {
      int b = t*16 + col;
      #pragma unroll
      for (int r = 0; r < 4; ++r)
        atomicAdd(&out[(size_t)b * HD + mrow + r], acc[t][r] * sc[r]);
    }
  }
}

// ---------------------------------------------------------------------------
extern "C" void kernel_launch(void* const* d_in, const int* in_sizes, int n_in,
                              void* d_out, int out_size, void* d_ws, size_t ws_size,
                              hipStream_t stream) {
  const float* x    = (const float*)d_in[0];
  const float* lutg = (const float*)d_in[1];
  const float* lutu = (const float*)d_in[2];
  const float* lutd = (const float*)d_in[3];
  const int*   gw   = (const int*)d_in[4];
  const int*   uw   = (const int*)d_in[5];
  const int*   dw   = (const int*)d_in[6];
  const float* gsl  = (const float*)d_in[7];
  const float* gsr  = (const float*)d_in[8];
  const float* usl  = (const float*)d_in[9];
  const float* usr  = (const float*)d_in[10];
  const float* dsl  = (const float*)d_in[11];
  const float* dsr  = (const float*)d_in[12];
  float* out = (float*)d_out;

  // ws layout: xg (512KB) | xu (512KB) | hidden (1.75MB)  -> ~2.75 MB total
  unsigned short* xg     = (unsigned short*)d_ws;
  unsigned short* xu     = xg + (size_t)NB * HD;
  unsigned short* hidden = xu + (size_t)NB * HD;

  hipMemsetAsync(d_out, 0, (size_t)NB * HD * sizeof(float), stream);
  prep_kernel<<<(NB*HD/4 + 255)/256, 256, 0, stream>>>(x, gsr, usr, xg, xu);
  gate_up_kernel<<<ID/16, 256, 0, stream>>>(gw, uw, lutg, lutu, xg, xu,
                                            gsl, usl, dsr, hidden);
  down_kernel<<<dim3(HD/16, DSPLIT), 256, 0, stream>>>(dw, lutd, hidden, dsl, out);
}

// Round 3
// 757.593 us; speedup vs baseline: 1.0969x; 1.0969x over previous
//
#include <hip/hip_runtime.h>
#include <hip/hip_bf16.h>

// Problem constants (fixed by the reference)
#define HD   4096      // hidden
#define ID   14336     // intermediate
#define NB   64        // batch
#define NLUTN 4096
#define GU_KS 4        // gate/up cross-block K split (K chunk = 1024)
#define D_KS  16       // down cross-block K split   (K chunk = 896)

typedef __attribute__((ext_vector_type(8))) short short8;   // 8 x bf16 bits
typedef __attribute__((ext_vector_type(4))) float f32x4;    // MFMA accumulator

__device__ __forceinline__ unsigned short f2bf(float f) {
  __hip_bfloat16 h = __float2bfloat16(f);
  return __builtin_bit_cast(unsigned short, h);
}

// async global->LDS DMA, 16 B per lane. LDS dest is wave-uniform base;
// HW writes lane i at base + i*16 B. (guide §5: width=16 verified on gfx950)
__device__ __forceinline__ void g2l16(const unsigned short* g, unsigned short* l) {
  __builtin_amdgcn_global_load_lds(
      (const __attribute__((address_space(1))) unsigned int*)g,
      (__attribute__((address_space(3))) unsigned int*)l, 16, 0, 0);
}

// ---------------------------------------------------------------------------
// prep: x'_g[b][h] = bf16(x[b][h]*gsr[h]), x'_u likewise. [b][k] row-major.
// ---------------------------------------------------------------------------
__global__ __launch_bounds__(256) void prep_kernel(
    const float* __restrict__ x, const float* __restrict__ gsr,
    const float* __restrict__ usr,
    unsigned short* __restrict__ xg, unsigned short* __restrict__ xu)
{
  int t = blockIdx.x * 256 + threadIdx.x;          // 0..65535 float4s
  float4 xv = ((const float4*)x)[t];
  int hs = t & (HD/4 - 1);
  float4 g = ((const float4*)gsr)[hs];
  float4 u = ((const float4*)usr)[hs];
  ((ushort4*)xg)[t] = make_ushort4(f2bf(xv.x*g.x), f2bf(xv.y*g.y), f2bf(xv.z*g.z), f2bf(xv.w*g.w));
  ((ushort4*)xu)[t] = make_ushort4(f2bf(xv.x*u.x), f2bf(xv.y*u.y), f2bf(xv.z*u.z), f2bf(xv.w*u.w));
}

// ---------------------------------------------------------------------------
// gate+up: block = 4 waves, M-strip = 64 I-rows (wave w owns rows 16w..16w+15),
// K chunk = 1024 per block, grid (ID/64, GU_KS) = (224, 4).
// B tiles (x'g, x'u: 64 batches x 32 k) staged double-buffered via
// global_load_lds, shared by all 4 waves; walks loaded per-lane int4 with
// 1-deep prefetch; A-frag = LDS LUT gather. f32 atomicAdd partials pg/pu.
// LDS: 16 KB LUTs + 16 KB tiles = 32 KB.
// ---------------------------------------------------------------------------
__global__ __launch_bounds__(256, 4) void gate_up_kernel(
    const int* __restrict__ gw, const int* __restrict__ uw,
    const float* __restrict__ lutg_f, const float* __restrict__ lutu_f,
    const unsigned short* __restrict__ xg, const unsigned short* __restrict__ xu,
    float* __restrict__ pg, float* __restrict__ pu)
{
  __shared__ unsigned short lutg[NLUTN];       // 8 KB
  __shared__ unsigned short lutu[NLUTN];       // 8 KB
  __shared__ unsigned short Bg[2][64*32];      // 2 x 4 KB
  __shared__ unsigned short Bu[2][64*32];      // 2 x 4 KB

  const int tid = threadIdx.x;
  #pragma unroll
  for (int i = tid; i < NLUTN/4; i += 256) {
    float4 g = ((const float4*)lutg_f)[i];
    float4 u = ((const float4*)lutu_f)[i];
    ((ushort4*)lutg)[i] = make_ushort4(f2bf(g.x), f2bf(g.y), f2bf(g.z), f2bf(g.w));
    ((ushort4*)lutu)[i] = make_ushort4(f2bf(u.x), f2bf(u.y), f2bf(u.z), f2bf(u.w));
  }

  const int lane = tid & 63;
  const int wv   = tid >> 6;
  const int col  = lane & 15;
  const int quad = lane >> 4;
  const int m0   = blockIdx.x * 64;
  const int mrow0 = m0 + wv * 16;
  const int kb   = blockIdx.y * (HD / GU_KS);
  const int KC   = HD / GU_KS;                 // 1024

  // staging source: wave w stages batch rows 16w..16w+15 (lane i -> row
  // 16w + i/4, 16 B quarter i%4); LDS dest base + lane*16 gives [row][32]
  const int srow = 16*wv + (lane >> 2);
  const int soff = (lane & 3) * 8;
  const unsigned short* xgs = xg + (size_t)srow * HD + kb + soff;
  const unsigned short* xus = xu + (size_t)srow * HD + kb + soff;

  const int* gp = gw + (size_t)(mrow0 + col) * HD + kb + quad * 8;
  const int* up = uw + (size_t)(mrow0 + col) * HD + kb + quad * 8;

  // stage iter 0 + prefetch iter-0 walks
  g2l16(xgs, &Bg[0][wv*512]);
  g2l16(xus, &Bu[0][wv*512]);
  int4 ga = *(const int4*)(gp);
  int4 gb = *(const int4*)(gp + 4);
  int4 ua = *(const int4*)(up);
  int4 ub = *(const int4*)(up + 4);
  __syncthreads();   // drains DMA + LUT staging

  const f32x4 z = {0.f, 0.f, 0.f, 0.f};
  f32x4 accg[4] = {z, z, z, z};
  f32x4 accu[4] = {z, z, z, z};

  for (int k0 = 0; k0 < KC; k0 += 32) {
    const int buf = (k0 >> 5) & 1;
    const int kn = k0 + 32;
    if (kn < KC) {
      g2l16(xgs + kn, &Bg[buf^1][wv*512]);
      g2l16(xus + kn, &Bu[buf^1][wv*512]);
    }
    int4 cga = ga, cgb = gb, cua = ua, cub = ub;
    const int knw = (kn < KC) ? kn : 0;
    ga = *(const int4*)(gp + knw);
    gb = *(const int4*)(gp + knw + 4);
    ua = *(const int4*)(up + knw);
    ub = *(const int4*)(up + knw + 4);

    short8 afg, afu;
    afg[0] = (short)lutg[cga.x]; afg[1] = (short)lutg[cga.y];
    afg[2] = (short)lutg[cga.z]; afg[3] = (short)lutg[cga.w];
    afg[4] = (short)lutg[cgb.x]; afg[5] = (short)lutg[cgb.y];
    afg[6] = (short)lutg[cgb.z]; afg[7] = (short)lutg[cgb.w];
    afu[0] = (short)lutu[cua.x]; afu[1] = (short)lutu[cua.y];
    afu[2] = (short)lutu[cua.z]; afu[3] = (short)lutu[cua.w];
    afu[4] = (short)lutu[cub.x]; afu[5] = (short)lutu[cub.y];
    afu[6] = (short)lutu[cub.z]; afu[7] = (short)lutu[cub.w];

    #pragma unroll
    for (int t = 0; t < 4; ++t) {
      short8 bgf = *(const short8*)&Bg[buf][(t*16 + col)*32 + quad*8];
      short8 buf_ = *(const short8*)&Bu[buf][(t*16 + col)*32 + quad*8];
      accg[t] = __builtin_amdgcn_mfma_f32_16x16x32_bf16(afg, bgf, accg[t], 0, 0, 0);
      accu[t] = __builtin_amdgcn_mfma_f32_16x16x32_bf16(afu, buf_, accu[t], 0, 0, 0);
    }
    __syncthreads();  // DMA for buf^1 done; all waves done reading buf
  }

  // epilogue: D layout col=lane&15 (batch), row=quad*4+reg (i)
  const int irow = mrow0 + quad * 4;
  #pragma unroll
  for (int t = 0; t < 4; ++t) {
    const int b = t*16 + col;
    float* pgb = pg + (size_t)b * ID + irow;
    float* pub = pu + (size_t)b * ID + irow;
    #pragma unroll
    for (int r = 0; r < 4; ++r) {
      atomicAdd(pgb + r, accg[t][r]);
      atomicAdd(pub + r, accu[t][r]);
    }
  }
}

// ---------------------------------------------------------------------------
// hidden epilogue: hidden[b][i] = bf16(silu(0.02*gsl*pg) * 0.02*usl*pu * dsr)
// ---------------------------------------------------------------------------
__global__ __launch_bounds__(256) void hidden_kernel(
    const float* __restrict__ pg, const float* __restrict__ pu,
    const float* __restrict__ gsl, const float* __restrict__ usl,
    const float* __restrict__ dsr,
    unsigned short* __restrict__ hidden)
{
  const int t = blockIdx.x * 256 + threadIdx.x;   // over NB*ID/4 = 229376
  const int I4 = ID / 4;
  const int b = t / I4, i4 = t % I4;
  float4 g4 = ((const float4*)pg)[(size_t)b * I4 + i4];
  float4 u4 = ((const float4*)pu)[(size_t)b * I4 + i4];
  float4 sg = ((const float4*)gsl)[i4];
  float4 su = ((const float4*)usl)[i4];
  float4 sd = ((const float4*)dsr)[i4];
  float g0 = g4.x * 0.02f * sg.x, u0 = u4.x * 0.02f * su.x;
  float g1 = g4.y * 0.02f * sg.y, u1 = u4.y * 0.02f * su.y;
  float g2 = g4.z * 0.02f * sg.z, u2 = u4.z * 0.02f * su.z;
  float g3 = g4.w * 0.02f * sg.w, u3 = u4.w * 0.02f * su.w;
  ushort4 hv;
  hv.x = f2bf((g0 / (1.f + __expf(-g0))) * u0 * sd.x);
  hv.y = f2bf((g1 / (1.f + __expf(-g1))) * u1 * sd.y);
  hv.z = f2bf((g2 / (1.f + __expf(-g2))) * u2 * sd.z);
  hv.w = f2bf((g3 / (1.f + __expf(-g3))) * u3 * sd.w);
  ((ushort4*)hidden)[(size_t)b * I4 + i4] = hv;
}

// ---------------------------------------------------------------------------
// down: block = 4 waves, M-strip = 64 h-rows, K chunk = 896, grid (64, D_KS).
// hidden tile staged double-buffered via global_load_lds (1 instr/wave/iter).
// f32 atomicAdd straight into out (zero-inited), scale 0.02*dsl fused.
// LDS: 8 KB LUT + 8 KB tiles = 16 KB.
// ---------------------------------------------------------------------------
__global__ __launch_bounds__(256, 4) void down_kernel(
    const int* __restrict__ dw, const float* __restrict__ lutd_f,
    const unsigned short* __restrict__ hidden,
    const float* __restrict__ dsl,
    float* __restrict__ out)
{
  __shared__ unsigned short lutd[NLUTN];       // 8 KB
  __shared__ unsigned short Bh[2][64*32];      // 2 x 4 KB

  const int tid = threadIdx.x;
  #pragma unroll
  for (int i = tid; i < NLUTN/4; i += 256) {
    float4 d = ((const float4*)lutd_f)[i];
    ((ushort4*)lutd)[i] = make_ushort4(f2bf(d.x), f2bf(d.y), f2bf(d.z), f2bf(d.w));
  }

  const int lane = tid & 63;
  const int wv   = tid >> 6;
  const int col  = lane & 15;
  const int quad = lane >> 4;
  const int m0   = blockIdx.x * 64;            // h strip
  const int mrow0 = m0 + wv * 16;
  const int kb   = blockIdx.y * (ID / D_KS);
  const int KC   = ID / D_KS;                  // 896

  const int srow = 16*wv + (lane >> 2);
  const int soff = (lane & 3) * 8;
  const unsigned short* hsrc = hidden + (size_t)srow * ID + kb + soff;

  const int* dp = dw + (size_t)(mrow0 + col) * ID + kb + quad * 8;

  g2l16(hsrc, &Bh[0][wv*512]);
  int4 da = *(const int4*)(dp);
  int4 db = *(const int4*)(dp + 4);
  __syncthreads();

  const f32x4 z = {0.f, 0.f, 0.f, 0.f};
  f32x4 acc[4] = {z, z, z, z};

  for (int k0 = 0; k0 < KC; k0 += 32) {
    const int buf = (k0 >> 5) & 1;
    const int kn = k0 + 32;
    if (kn < KC) g2l16(hsrc + kn, &Bh[buf^1][wv*512]);
    int4 cda = da, cdb = db;
    const int knw = (kn < KC) ? kn : 0;
    da = *(const int4*)(dp + knw);
    db = *(const int4*)(dp + knw + 4);

    short8 af;
    af[0] = (short)lutd[cda.x]; af[1] = (short)lutd[cda.y];
    af[2] = (short)lutd[cda.z]; af[3] = (short)lutd[cda.w];
    af[4] = (short)lutd[cdb.x]; af[5] = (short)lutd[cdb.y];
    af[6] = (short)lutd[cdb.z]; af[7] = (short)lutd[cdb.w];

    #pragma unroll
    for (int t = 0; t < 4; ++t) {
      short8 bh = *(const short8*)&Bh[buf][(t*16 + col)*32 + quad*8];
      acc[t] = __builtin_amdgcn_mfma_f32_16x16x32_bf16(af, bh, acc[t], 0, 0, 0);
    }
    __syncthreads();
  }

  const int hrow = mrow0 + quad * 4;
  float sc[4];
  #pragma unroll
  for (int r = 0; r < 4; ++r) sc[r] = 0.02f * dsl[hrow + r];
  #pragma unroll
  for (int t = 0; t < 4; ++t) {
    const int b = t*16 + col;
    float* ob = out + (size_t)b * HD + hrow;
    #pragma unroll
    for (int r = 0; r < 4; ++r)
      atomicAdd(ob + r, acc[t][r] * sc[r]);
  }
}

// ---------------------------------------------------------------------------
extern "C" void kernel_launch(void* const* d_in, const int* in_sizes, int n_in,
                              void* d_out, int out_size, void* d_ws, size_t ws_size,
                              hipStream_t stream) {
  const float* x    = (const float*)d_in[0];
  const float* lutg = (const float*)d_in[1];
  const float* lutu = (const float*)d_in[2];
  const float* lutd = (const float*)d_in[3];
  const int*   gw   = (const int*)d_in[4];
  const int*   uw   = (const int*)d_in[5];
  const int*   dw   = (const int*)d_in[6];
  const float* gsl  = (const float*)d_in[7];
  const float* gsr  = (const float*)d_in[8];
  const float* usl  = (const float*)d_in[9];
  const float* usr  = (const float*)d_in[10];
  const float* dsl  = (const float*)d_in[11];
  const float* dsr  = (const float*)d_in[12];
  float* out = (float*)d_out;

  // ws layout: xg (512K) | xu (512K) | hidden (1.75M) | pg (3.5M) | pu (3.5M)
  unsigned short* xg     = (unsigned short*)d_ws;
  unsigned short* xu     = xg + (size_t)NB * HD;
  unsigned short* hidden = xu + (size_t)NB * HD;
  float* pg = (float*)(hidden + (size_t)NB * ID);
  float* pu = pg + (size_t)NB * ID;

  hipMemsetAsync(d_out, 0, (size_t)NB * HD * sizeof(float), stream);
  hipMemsetAsync(pg, 0, (size_t)2 * NB * ID * sizeof(float), stream);
  prep_kernel<<<(NB*HD/4 + 255)/256, 256, 0, stream>>>(x, gsr, usr, xg, xu);
  gate_up_kernel<<<dim3(ID/64, GU_KS), 256, 0, stream>>>(gw, uw, lutg, lutu,
                                                         xg, xu, pg, pu);
  hidden_kernel<<<(NB*ID/4 + 255)/256, 256, 0, stream>>>(pg, pu, gsl, usl, dsr,
                                                         hidden);
  down_kernel<<<dim3(HD/64, D_KS), 256, 0, stream>>>(dw, lutd, hidden, dsl, out);
}